// Round 6
// baseline (186.472 us; speedup 1.0000x reference)
//
#include <hip/hip_runtime.h>

// Problem constants (B=2, C=256, H=W=48, d_model=256, 8 heads, d_k=32)
// Inputs/outputs fp32. Internals bf16; all three matmuls + attention on MFMA.
#define HW 2304
#define SW 48
#define DMODEL 256
#define NHEADS 8
#define DK 32
#define BATCH 2

typedef unsigned short u16;
typedef __attribute__((ext_vector_type(8))) short short8;
typedef __attribute__((ext_vector_type(4))) float f32x4;

__device__ __forceinline__ float bf2f(u16 v) {
  union { unsigned int u; float f; } c; c.u = ((unsigned int)v) << 16; return c.f;
}
__device__ __forceinline__ u16 f2bf(float f) {
  union { unsigned int u; float f; } c; c.f = f;
  unsigned int u = c.u;
  unsigned int r = (u + 0x7FFFu + ((u >> 16) & 1u)) >> 16;
  return (u16)r;
}
// exact floor(n/48) for n in [0, 2304): magic 87382 = (2^22+32)/48
__device__ __forceinline__ int div48(int n) { return (n * 87382) >> 22; }

#define DTAB_N 9032  // 95*95 = 9025, padded to multiple of 8

// ---------------------------------------------------------------------------
// prep: [0,288) transpose x -> xt[b][n][c] bf16 ; [288,544) W fp32->bf16 concat
// [q|k|v|o] ; [544,580) dtab bf16. grid 580, block 256.
__global__ __launch_bounds__(256) void prep_kernel(
    const float* __restrict__ x,
    const float* __restrict__ Wq, const float* __restrict__ Wk,
    const float* __restrict__ Wv, const float* __restrict__ Wo,
    const float* __restrict__ lam_p,
    u16* __restrict__ xt, u16* __restrict__ Wb, u16* __restrict__ dtabb) {
  int bid = blockIdx.x;
  int t = threadIdx.x;
  if (bid < 288) {
    // transpose one 64c x 64n tile of x into xt
    int b = bid / 144, r = bid % 144;
    int c0 = (r / 36) * 64, n0 = (r % 36) * 64;
    __shared__ u16 sh[64][72];
#pragma unroll
    for (int p = 0; p < 4; ++p) {
      int row = (t >> 4) + p * 16;        // c index
      int col4 = (t & 15) * 4;            // n offset
      float4 v = *(const float4*)(x + (size_t)(b * DMODEL + c0 + row) * HW +
                                  n0 + col4);
      sh[col4 + 0][row] = f2bf(v.x);
      sh[col4 + 1][row] = f2bf(v.y);
      sh[col4 + 2][row] = f2bf(v.z);
      sh[col4 + 3][row] = f2bf(v.w);
    }
    __syncthreads();
#pragma unroll
    for (int q = 0; q < 2; ++q) {
      int nrow = t >> 2;
      int c8 = (t & 3) * 8 + q * 32;
      *(uint4*)(xt + (size_t)(b * HW + n0 + nrow) * DMODEL + c0 + c8) =
          *(const uint4*)&sh[nrow][c8];
    }
  } else if (bid < 544) {
    int idx = (bid - 288) * 1024 + t * 4;
    int which = idx >> 16, off = idx & 65535;
    const float* src = (which == 0) ? Wq : (which == 1) ? Wk
                       : (which == 2) ? Wv : Wo;
    float4 v = *(const float4*)(src + off);
    ushort4 ov;
    ov.x = f2bf(v.x); ov.y = f2bf(v.y); ov.z = f2bf(v.z); ov.w = f2bf(v.w);
    *(ushort4*)(Wb + idx) = ov;
  } else {
    int id = (bid - 544) * 256 + t;
    if (id < DTAB_N) {
      float v = 0.f;
      if (id < 95 * 95) {
        float lam = lam_p[0];
        int dyi = id / 95, dxi = id - dyi * 95;
        float dy = (float)(dyi - 47), dx = (float)(dxi - 47);
        v = lam * expf(-sqrtf(dy * dy + dx * dx));
      }
      dtabb[id] = f2bf(v);
    }
  }
}

// ---------------------------------------------------------------------------
// QKV projection, LDS-free MFMA GEMM. block = 64 m-rows x 64 n-cols, 4 waves;
// wave w owns m-rows [w*16, w*16+16). Frags loaded direct from global (16B).
//   Q -> qt[b][h][n][32] (bias+pe, *1/sqrt32) ; K -> kt same ; V -> vb[b][c][n]
// grid (36, 12, 2), block 256.
__global__ __launch_bounds__(256) void qkv_kernel(
    const u16* __restrict__ Wb, const u16* __restrict__ xt,
    const float* __restrict__ bq, const float* __restrict__ bk,
    const float* __restrict__ bv,
    u16* __restrict__ qt, u16* __restrict__ ktb, u16* __restrict__ vb) {
  int t = threadIdx.x;
  int w = t >> 6, lane = t & 63, lo = lane & 15, quad = lane >> 4;
  int n0 = blockIdx.x * 64;
  int mb = blockIdx.y, b = blockIdx.z;
  int which = mb >> 2;
  int mrel0 = (mb & 3) * 64;
  const u16* A = Wb + which * 65536;
  const float* bias = (which == 0) ? bq : (which == 1) ? bk : bv;
  const u16* Bx = xt + (size_t)b * HW * DMODEL;

  f32x4 acc[4] = {{0.f, 0.f, 0.f, 0.f}, {0.f, 0.f, 0.f, 0.f},
                  {0.f, 0.f, 0.f, 0.f}, {0.f, 0.f, 0.f, 0.f}};
#pragma unroll
  for (int k0 = 0; k0 < DMODEL; k0 += 32) {
    short8 af = *(const short8*)(A + (size_t)(mrel0 + w * 16 + lo) * DMODEL +
                                 k0 + quad * 8);
#pragma unroll
    for (int nt = 0; nt < 4; ++nt) {
      short8 bf_ = *(const short8*)(Bx + (size_t)(n0 + nt * 16 + lo) * DMODEL +
                                    k0 + quad * 8);
      acc[nt] = __builtin_amdgcn_mfma_f32_16x16x32_bf16(af, bf_, acc[nt], 0, 0, 0);
    }
  }

  int mbase = mrel0 + w * 16 + quad * 4;  // 4-aligned
  if (which == 2) {
    // V: scalar bf16 stores [b][c][n]
#pragma unroll
    for (int reg = 0; reg < 4; ++reg) {
      int mrel = mbase + reg;
      float bi = bias[mrel];
      u16* dst = vb + (size_t)(b * DMODEL + mrel) * HW + n0 + lo;
#pragma unroll
      for (int nt = 0; nt < 4; ++nt) dst[nt * 16] = f2bf(acc[nt][reg] + bi);
    }
  } else {
    float sc = (which == 0) ? 0.17677669529663687f : 1.0f;
    int h = mbase >> 5, d0 = mbase & 31;
    u16* base = ((which == 0) ? qt : ktb) + (size_t)(b * NHEADS + h) * HW * DK;
    float bi[4], dv[4];
    bool usecos[4], usey[4];
#pragma unroll
    for (int reg = 0; reg < 4; ++reg) {
      int mrel = mbase + reg;
      bi[reg] = bias[mrel];
      int oo = mrel & 127;
      dv[reg] = expf(-0.07195578415606394f * (float)(oo & ~1));
      usecos[reg] = (oo & 1);
      usey[reg] = (mrel >= 128);
    }
#pragma unroll
    for (int nt = 0; nt < 4; ++nt) {
      int n = n0 + nt * 16 + lo;
      int yy = div48(n), xx = n - yy * SW;
      ushort4 ov;
      float vals[4];
#pragma unroll
      for (int reg = 0; reg < 4; ++reg) {
        float tv = (usey[reg] ? (float)yy : (float)xx) * dv[reg];
        float pe = usecos[reg] ? cosf(tv) : sinf(tv);
        vals[reg] = (acc[nt][reg] + bi[reg] + pe) * sc;
      }
      ov.x = f2bf(vals[0]); ov.y = f2bf(vals[1]);
      ov.z = f2bf(vals[2]); ov.w = f2bf(vals[3]);
      *(ushort4*)(base + (size_t)n * DK + d0) = ov;
    }
  }
}

// ---------------------------------------------------------------------------
// MFMA flash attention, fixed-max softmax, dtab in LDS.
// BARRIER-FREE main loop: K and V fragments are contiguous 16B/lane in global
// (L1-served, shared across the block's 4 waves); only P round-trips through
// LDS, and its region is per-wave private -> no __syncthreads in the k-loop.
// grid (36, 8, 2), block 256.
__global__ __launch_bounds__(256) void attn_kernel(
    const u16* __restrict__ qt, const u16* __restrict__ ktb,
    const u16* __restrict__ vb, const u16* __restrict__ dtabb,
    u16* __restrict__ aot) {
  int t = threadIdx.x;
  int w = t >> 6;
  int lane = t & 63;
  int lo = lane & 15, quad = lane >> 4;
  int n0 = blockIdx.x * 64;
  int h = blockIdx.y, b = blockIdx.z;

  __shared__ __align__(16) u16 dsh[DTAB_N];  // 18064 B
  __shared__ u16 Ps[4 * 16 * 72];            // per-wave private regions

  for (int i = t; i < DTAB_N / 8; i += 256)
    *(uint4*)&dsh[i * 8] = *(const uint4*)&dtabb[i * 8];
  __syncthreads();  // dsh visible to all waves; the ONLY barrier

  const u16* qtg = qt + (size_t)(b * NHEADS + h) * HW * DK;
  const u16* ktg = ktb + (size_t)(b * NHEADS + h) * HW * DK;
  const u16* vbg = vb + (size_t)(b * DMODEL + h * DK) * HW;

  short8 qf = *(const short8*)(qtg + (size_t)(n0 + w * 16 + lo) * DK + quad * 8);

  int a_i[4];
#pragma unroll
  for (int reg = 0; reg < 4; ++reg) {
    int n = n0 + w * 16 + quad * 4 + reg;
    int y1 = div48(n), x1 = n - y1 * SW;
    a_i[reg] = y1 * 95 + x1 + 4512;
  }

  f32x4 o0 = {0.f, 0.f, 0.f, 0.f}, o1 = {0.f, 0.f, 0.f, 0.f};
  float lsum[4] = {0.f, 0.f, 0.f, 0.f};
  u16* psw = Ps + w * 16 * 72;

  for (int kt = 0; kt < 36; ++kt) {
    int m0 = kt * 64;

    // S = Q K^T : K-frag direct from global, K[m=t4*16+lo][d=quad*8..]
    f32x4 s[4];
#pragma unroll
    for (int t4 = 0; t4 < 4; ++t4) {
      short8 kf =
          *(const short8*)(ktg + (size_t)(m0 + t4 * 16 + lo) * DK + quad * 8);
      f32x4 z = {0.f, 0.f, 0.f, 0.f};
      s[t4] = __builtin_amdgcn_mfma_f32_16x16x32_bf16(qf, kf, z, 0, 0, 0);
    }
    // P = exp(S + dist bias from LDS); rowsums; store P (bf16, per-wave LDS)
#pragma unroll
    for (int t4 = 0; t4 < 4; ++t4) {
      int m = m0 + t4 * 16 + lo;
      int y2 = div48(m), x2 = m - y2 * SW;
      int bj = y2 * 95 + x2;
#pragma unroll
      for (int reg = 0; reg < 4; ++reg) {
        float p = __expf(s[t4][reg] + bf2f(dsh[a_i[reg] - bj]));
        lsum[reg] += p;
        psw[(quad * 4 + reg) * 72 + t4 * 16 + lo] = f2bf(p);
      }
    }
    // O += P V : A-frag = P from per-wave LDS; B-frag = V^T direct from global
    //   V^T[d=lo][m=ks*32+quad*8+j] == vb row (h*32+d), pos m0+ks*32+quad*8..
#pragma unroll
    for (int ks = 0; ks < 2; ++ks) {
      short8 af = *(const short8*)&psw[lo * 72 + ks * 32 + quad * 8];
      short8 v0 =
          *(const short8*)(vbg + (size_t)lo * HW + m0 + ks * 32 + quad * 8);
      o0 = __builtin_amdgcn_mfma_f32_16x16x32_bf16(af, v0, o0, 0, 0, 0);
      short8 v1 = *(const short8*)(vbg + (size_t)(16 + lo) * HW + m0 +
                                   ks * 32 + quad * 8);
      o1 = __builtin_amdgcn_mfma_f32_16x16x32_bf16(af, v1, o1, 0, 0, 0);
    }
  }

#pragma unroll
  for (int d = 1; d < 16; d <<= 1) {
#pragma unroll
    for (int reg = 0; reg < 4; ++reg) lsum[reg] += __shfl_xor(lsum[reg], d);
  }

  // write aot[b][n][h*32 + dd] (bf16), dd = lo / 16+lo
  u16* aog = aot + (size_t)b * HW * DMODEL + h * DK;
#pragma unroll
  for (int reg = 0; reg < 4; ++reg) {
    int n = n0 + w * 16 + quad * 4 + reg;
    float inv = 1.0f / lsum[reg];
    aog[(size_t)n * DMODEL + lo] = f2bf(o0[reg] * inv);
    aog[(size_t)n * DMODEL + 16 + lo] = f2bf(o1[reg] * inv);
  }
}

// ---------------------------------------------------------------------------
// out[b][c][n] = x + gamma * (Wo ao)[c][n] + bo[c], LDS-free MFMA GEMM.
// grid (36, 4, 2), block 256.
__global__ __launch_bounds__(256) void out_kernel(
    const float* __restrict__ x, const u16* __restrict__ Wob,
    const float* __restrict__ bo, const float* __restrict__ gp,
    const u16* __restrict__ aot, float* __restrict__ out) {
  int t = threadIdx.x;
  int w = t >> 6, lane = t & 63, lo = lane & 15, quad = lane >> 4;
  int n0 = blockIdx.x * 64;
  int c0 = blockIdx.y * 64;
  int b = blockIdx.z;
  float gamma = gp[0];
  const u16* Ba = aot + (size_t)b * HW * DMODEL;

  f32x4 acc[4] = {{0.f, 0.f, 0.f, 0.f}, {0.f, 0.f, 0.f, 0.f},
                  {0.f, 0.f, 0.f, 0.f}, {0.f, 0.f, 0.f, 0.f}};
#pragma unroll
  for (int k0 = 0; k0 < DMODEL; k0 += 32) {
    short8 af = *(const short8*)(Wob + (size_t)(c0 + w * 16 + lo) * DMODEL +
                                 k0 + quad * 8);
#pragma unroll
    for (int nt = 0; nt < 4; ++nt) {
      short8 bf_ = *(const short8*)(Ba + (size_t)(n0 + nt * 16 + lo) * DMODEL +
                                    k0 + quad * 8);
      acc[nt] = __builtin_amdgcn_mfma_f32_16x16x32_bf16(af, bf_, acc[nt], 0, 0, 0);
    }
  }

#pragma unroll
  for (int reg = 0; reg < 4; ++reg) {
    int c = c0 + w * 16 + quad * 4 + reg;
    float bi = bo[c];
    const float* xs = x + (size_t)(b * DMODEL + c) * HW + n0 + lo;
    float* os = out + (size_t)(b * DMODEL + c) * HW + n0 + lo;
#pragma unroll
    for (int nt = 0; nt < 4; ++nt)
      os[nt * 16] = xs[nt * 16] + gamma * acc[nt][reg] + bi;
  }
}

// ---------------------------------------------------------------------------
extern "C" void kernel_launch(void* const* d_in, const int* in_sizes, int n_in,
                              void* d_out, int out_size, void* d_ws,
                              size_t ws_size, hipStream_t stream) {
  const float* x   = (const float*)d_in[0];
  const float* Wq  = (const float*)d_in[1];
  const float* bq  = (const float*)d_in[2];
  const float* Wk  = (const float*)d_in[3];
  const float* bk  = (const float*)d_in[4];
  const float* Wv  = (const float*)d_in[5];
  const float* bv  = (const float*)d_in[6];
  const float* Wo  = (const float*)d_in[7];
  const float* bo  = (const float*)d_in[8];
  const float* lam = (const float*)d_in[9];
  const float* gam = (const float*)d_in[10];

  // ws layout (bytes), total ~10.0 MB (validated budget 11.3 MB):
  //   dtabb bf16 [0, 18064)            (region reserved to 36864)
  //   Wb    bf16 [36864, 561152)       4*65536*2, order [q|k|v|o]
  //   xt    bf16 [561152, 2920448)     2*2304*256 — ALIASED with aot (xt dead
  //                                    after qkv_kernel; attn writes aot)
  //   qt    bf16 [2920448, 5279744)
  //   ktb   bf16 [5279744, 7639040)
  //   vb    bf16 [7639040, 9998336)
  char* wsb = (char*)d_ws;
  u16* dtabb = (u16*)wsb;
  u16* Wb  = (u16*)(wsb + 36864);
  u16* xt  = (u16*)(wsb + 561152);
  u16* aot = xt;  // alias, sequential lifetime
  u16* qt  = (u16*)(wsb + 2920448);
  u16* ktb = (u16*)(wsb + 5279744);
  u16* vb  = (u16*)(wsb + 7639040);
  float* out = (float*)d_out;

  prep_kernel<<<dim3(580), 256, 0, stream>>>(x, Wq, Wk, Wv, Wo, lam,
                                             xt, Wb, dtabb);
  qkv_kernel<<<dim3(36, 12, BATCH), 256, 0, stream>>>(Wb, xt, bq, bk, bv,
                                                      qt, ktb, vb);
  attn_kernel<<<dim3(36, NHEADS, BATCH), 256, 0, stream>>>(qt, ktb, vb, dtabb,
                                                           aot);
  out_kernel<<<dim3(36, 4, BATCH), 256, 0, stream>>>(x, Wb + 3 * 65536, bo, gam,
                                                     aot, out);
}